// Round 14
// baseline (318.953 us; speedup 1.0000x reference)
//
#include <hip/hip_runtime.h>
#include <hip/hip_bf16.h>

#define N_NODES 50000
#define E0      800000
#define ETOT    850000

typedef __bf16 bf16x8 __attribute__((ext_vector_type(8)));
typedef float  f32x4  __attribute__((ext_vector_type(4)));
typedef ushort u16x8  __attribute__((ext_vector_type(8)));
union B8 { u16x8 u; bf16x8 b; };

static __device__ __forceinline__ float b2f(ushort u) {
    union { uint u; float f; } x; x.u = ((uint)u) << 16; return x.f;
}
static __device__ __forceinline__ ushort f2bf(float f) {
    uint u = __builtin_bit_cast(uint, f);
    uint r = (u + 0x7FFFu + ((u >> 16) & 1u)) >> 16;   // RNE; inputs finite
    return (ushort)r;
}

// ---------------- CSR build ----------------

__global__ __launch_bounds__(256) void k_deg(const int* __restrict__ ei, int* __restrict__ deg) {
    int e = blockIdx.x * 256 + threadIdx.x;
    if (e >= ETOT) return;
    int dst = (e < E0) ? ei[E0 + e] : (e - E0);
    atomicAdd(&deg[dst], 1);
}

__global__ __launch_bounds__(256) void k_scan1(const int* __restrict__ deg, int* __restrict__ offs,
                                               int* __restrict__ bsum) {
    __shared__ int buf[256];
    int tid = threadIdx.x;
    int i = blockIdx.x * 256 + tid;
    int v = (i < N_NODES) ? deg[i] : 0;
    buf[tid] = v;
    __syncthreads();
    for (int off = 1; off < 256; off <<= 1) {
        int t = (tid >= off) ? buf[tid - off] : 0;
        __syncthreads();
        buf[tid] += t;
        __syncthreads();
    }
    if (i < N_NODES) offs[i + 1] = buf[tid];
    if (tid == 255) bsum[blockIdx.x] = buf[255];
}

__global__ __launch_bounds__(256) void k_scan2(int* __restrict__ bsum, int nb) {
    __shared__ int buf[256];
    int tid = threadIdx.x;
    int v = (tid < nb) ? bsum[tid] : 0;
    buf[tid] = v;
    __syncthreads();
    for (int off = 1; off < 256; off <<= 1) {
        int t = (tid >= off) ? buf[tid - off] : 0;
        __syncthreads();
        buf[tid] += t;
        __syncthreads();
    }
    if (tid < nb) bsum[tid] = buf[tid] - v;
}

// also fills cursor (saves a kernel)
__global__ __launch_bounds__(256) void k_scan3(int* __restrict__ offs, const int* __restrict__ bsum,
                                               int* __restrict__ cursor) {
    int tid = threadIdx.x;
    int i = blockIdx.x * 256 + tid;
    if (i < N_NODES) {
        int v = offs[i + 1] + bsum[blockIdx.x];
        offs[i + 1] = v;
        cursor[i + 1] = v;
    }
    if (i == 0) { offs[0] = 0; cursor[0] = 0; }
}

__global__ __launch_bounds__(256) void k_scatter(const int* __restrict__ ei, int* __restrict__ cursor,
                                                 int* __restrict__ esrc) {
    int e = blockIdx.x * 256 + threadIdx.x;
    if (e >= ETOT) return;
    int src, dst;
    if (e < E0) { src = ei[e]; dst = ei[E0 + e]; }
    else        { src = e - E0; dst = src; }
    int pos = atomicAdd(&cursor[dst], 1);
    esrc[pos] = src;
}

// W [K][N] fp32 -> Wt_hi/Wt_lo [N][K] bf16 (tiny)
__global__ __launch_bounds__(256) void k_splitT(const float* __restrict__ W, ushort* __restrict__ th,
                                                ushort* __restrict__ tl, int K, int N) {
    int i = blockIdx.x * 256 + threadIdx.x;
    if (i >= K * N) return;
    int n = i / K, k = i - n * K;
    float v = W[(size_t)k * N + n];
    ushort h = f2bf(v);
    th[(size_t)n * K + k] = h;
    tl[(size_t)n * K + k] = f2bf(v - b2f(h));
}

// fp32 -> single RNE bf16 (for GEMM A)
__global__ __launch_bounds__(256) void k_split1(const float* __restrict__ in, ushort* __restrict__ out, int n4) {
    int i = blockIdx.x * 256 + threadIdx.x;
    if (i >= n4) return;
    float4 v = *(const float4*)(in + (size_t)i * 4);
    ushort4 h;
    h.x = f2bf(v.x); h.y = f2bf(v.y); h.z = f2bf(v.z); h.w = f2bf(v.w);
    *(ushort4*)(out + (size_t)i * 4) = h;
}

// ---------------- MFMA GEMM: A bf16, B hi/lo LDS dbuf, 128x64 tile ----------------
// Cb[M][Nn](bf16) = Ab[M][K=256](bf16) @ (Bth+Btl)[Nn][K]^T
// 4 waves, each 64 rows x 32 cols (4m x 2n frags). BK=64 windows, LDS 32 KB
// -> 4 blocks/CU co-resident (16 waves/CU) for cross-block latency hiding.
// 2 MFMA streams: A*Bh + A*Bl.

__global__ __launch_bounds__(256, 4) void k_gemm_mfma(const ushort* __restrict__ Ab,
                                                      const ushort* __restrict__ Bth,
                                                      const ushort* __restrict__ Btl,
                                                      ushort* __restrict__ Cb, int M, int Nn) {
    constexpr int K = 256;
    __shared__ ushort lds[2][2][8][64][8];       // 32 KB: buf, hi/lo, blk, col, 8
    int tid = threadIdx.x;
    int wid = tid >> 6, lane = tid & 63;
    int wr = wid >> 1, wc = wid & 1;             // 2x2: row-band 64, col-half 32
    int bm = blockIdx.x * 128, bn = blockIdx.y * 64;
    int lr = lane & 15, lg = lane >> 4;

    // staging role: sa = hi/lo array, half = which 4 chunks, scol = column
    int sa = tid >> 7, half = (tid >> 6) & 1, scol = tid & 63;
    const ushort* sb = (sa ? Btl : Bth) + (size_t)(bn + scol) * K + half * 32;

    const ushort* Ap[4];
#pragma unroll
    for (int m = 0; m < 4; ++m) {
        int row = bm + wr * 64 + m * 16 + lr;
        if (row >= M) row = M - 1;
        Ap[m] = Ab + (size_t)row * K + lg * 8;
    }

    f32x4 acc[4][2] = {};
    u16x8 sv[4];
    bf16x8 aH[2][4];

    // prologue: stage window 0, prefetch A steps 0,1
#pragma unroll
    for (int c = 0; c < 4; ++c) sv[c] = *(const u16x8*)(sb + c * 8);
#pragma unroll
    for (int m = 0; m < 4; ++m) {
        aH[0][m] = *(const bf16x8*)(Ap[m]);
        aH[1][m] = *(const bf16x8*)(Ap[m] + 32);
    }
#pragma unroll
    for (int c = 0; c < 4; ++c) *(u16x8*)&lds[0][sa][half * 4 + c][scol][0] = sv[c];
    __syncthreads();

#pragma unroll
    for (int s = 0; s < 8; ++s) {               // K32 steps; window w = s/2
        const int w = s >> 1, buf = w & 1, kk = s & 1;
        if (kk == 0 && w < 3) {                 // issue next window's B loads
#pragma unroll
            for (int c = 0; c < 4; ++c) sv[c] = *(const u16x8*)(sb + (w + 1) * 64 + c * 8);
        }
        bf16x8 bh[2], bl[2];
#pragma unroll
        for (int n = 0; n < 2; ++n) {
            int col = wc * 32 + n * 16 + lr;
            B8 th, tl2;
            th.u = *(const u16x8*)&lds[buf][0][kk * 4 + lg][col][0];
            tl2.u = *(const u16x8*)&lds[buf][1][kk * 4 + lg][col][0];
            bh[n] = th.b; bl[n] = tl2.b;
        }
        bf16x8 ah[4];
#pragma unroll
        for (int m = 0; m < 4; ++m) ah[m] = aH[s & 1][m];
        if (s < 6) {                            // refill this slot for step s+2
#pragma unroll
            for (int m = 0; m < 4; ++m) aH[s & 1][m] = *(const bf16x8*)(Ap[m] + (s + 2) * 32);
        }
#pragma unroll
        for (int m = 0; m < 4; ++m)
#pragma unroll
            for (int n = 0; n < 2; ++n) {
                acc[m][n] = __builtin_amdgcn_mfma_f32_16x16x32_bf16(ah[m], bh[n], acc[m][n], 0, 0, 0);
                acc[m][n] = __builtin_amdgcn_mfma_f32_16x16x32_bf16(ah[m], bl[n], acc[m][n], 0, 0, 0);
            }
        if (kk == 1 && w < 3) {                 // commit next window into other buffer
#pragma unroll
            for (int c = 0; c < 4; ++c) *(u16x8*)&lds[buf ^ 1][sa][half * 4 + c][scol][0] = sv[c];
            __syncthreads();
        }
    }
    // C/D layout: col = lane&15, row = (lane>>4)*4 + reg   [m89-verified]
#pragma unroll
    for (int m = 0; m < 4; ++m)
#pragma unroll
        for (int r = 0; r < 4; ++r) {
            int row = bm + wr * 64 + m * 16 + lg * 4 + r;
            if (row < M) {
#pragma unroll
                for (int n = 0; n < 2; ++n) {
                    int col = bn + wc * 32 + n * 16 + lr;
                    Cb[(size_t)row * Nn + col] = f2bf(acc[m][n][r]);
                }
            }
        }
}

// ---------------- per-node kernels (one wave / node), bf16 h rows ----------------

template <int F>
__global__ __launch_bounds__(256) void k_alpha(const ushort* __restrict__ H, const float* __restrict__ a_src,
                                               const float* __restrict__ a_dst, float* __restrict__ as,
                                               float* __restrict__ ad) {
    int gw = (blockIdx.x * 256 + threadIdx.x) >> 6;
    int lane = threadIdx.x & 63;
    if (gw >= N_NODES) return;
    float s = 0.f, d = 0.f;
    if (F == 256) {
        ushort4 v = *(const ushort4*)(H + (size_t)gw * 256 + lane * 4);
        float4 cs = *(const float4*)(a_src + lane * 4);
        float4 cd = *(const float4*)(a_dst + lane * 4);
        float f0 = b2f(v.x), f1 = b2f(v.y), f2 = b2f(v.z), f3 = b2f(v.w);
        s = f0 * cs.x + f1 * cs.y + f2 * cs.z + f3 * cs.w;
        d = f0 * cd.x + f1 * cd.y + f2 * cd.z + f3 * cd.w;
    } else {
        ushort2 v = *(const ushort2*)(H + (size_t)gw * 128 + lane * 2);
        float2 cs = *(const float2*)(a_src + lane * 2);
        float2 cd = *(const float2*)(a_dst + lane * 2);
        float f0 = b2f(v.x), f1 = b2f(v.y);
        s = f0 * cs.x + f1 * cs.y;
        d = f0 * cd.x + f1 * cd.y;
    }
    for (int o = 32; o; o >>= 1) { s += __shfl_down(s, o); d += __shfl_down(d, o); }
    if (lane == 0) { as[gw] = s; ad[gw] = d; }
}

// ---- fused online-softmax aggregation, 4-edge unrolled + deferred rescale ----
// WB: also write RNE-bf16 copy of the (relu'd) result for the next layer's GEMM A.
template <int F, bool RELU, bool WB>
__global__ __launch_bounds__(256) void k_aggf(const int* __restrict__ offs, const int* __restrict__ esrc,
                                              const float* __restrict__ as, const float* __restrict__ ad,
                                              const ushort* __restrict__ H, const float* __restrict__ bias,
                                              float* __restrict__ out, ushort* __restrict__ hb) {
    constexpr int V = F / 64;
    constexpr float THR = 8.f;
    int gw = (blockIdx.x * 256 + threadIdx.x) >> 6;
    int lane = threadIdx.x & 63;
    if (gw >= N_NODES) return;
    int s0 = offs[gw], s1 = offs[gw + 1];
    float adi = ad[gw];
    float m = -1e30f, ssum = 0.f;
    float acc[V] = {};
    int k = s0;
    for (; k + 3 < s1; k += 4) {
        int r0 = esrc[k], r1 = esrc[k + 1], r2 = esrc[k + 2], r3 = esrc[k + 3];
        float row0[V], row1[V], row2[V], row3[V];
        if (V == 4) {
            ushort4 v0 = *(const ushort4*)(H + (size_t)r0 * F + lane * 4);
            ushort4 v1 = *(const ushort4*)(H + (size_t)r1 * F + lane * 4);
            ushort4 v2 = *(const ushort4*)(H + (size_t)r2 * F + lane * 4);
            ushort4 v3 = *(const ushort4*)(H + (size_t)r3 * F + lane * 4);
            row0[0] = b2f(v0.x); row0[1] = b2f(v0.y); row0[2] = b2f(v0.z); row0[3] = b2f(v0.w);
            row1[0] = b2f(v1.x); row1[1] = b2f(v1.y); row1[2] = b2f(v1.z); row1[3] = b2f(v1.w);
            row2[0] = b2f(v2.x); row2[1] = b2f(v2.y); row2[2] = b2f(v2.z); row2[3] = b2f(v2.w);
            row3[0] = b2f(v3.x); row3[1] = b2f(v3.y); row3[2] = b2f(v3.z); row3[3] = b2f(v3.w);
        } else {
            ushort2 v0 = *(const ushort2*)(H + (size_t)r0 * F + lane * 2);
            ushort2 v1 = *(const ushort2*)(H + (size_t)r1 * F + lane * 2);
            ushort2 v2 = *(const ushort2*)(H + (size_t)r2 * F + lane * 2);
            ushort2 v3 = *(const ushort2*)(H + (size_t)r3 * F + lane * 2);
            row0[0] = b2f(v0.x); row0[1] = b2f(v0.y);
            row1[0] = b2f(v1.x); row1[1] = b2f(v1.y);
            row2[0] = b2f(v2.x); row2[1] = b2f(v2.y);
            row3[0] = b2f(v3.x); row3[1] = b2f(v3.y);
        }
        float e0 = as[r0] + adi; e0 = e0 > 0.f ? e0 : 0.2f * e0;
        float e1 = as[r1] + adi; e1 = e1 > 0.f ? e1 : 0.2f * e1;
        float e2 = as[r2] + adi; e2 = e2 > 0.f ? e2 : 0.2f * e2;
        float e3 = as[r3] + adi; e3 = e3 > 0.f ? e3 : 0.2f * e3;
        float em = fmaxf(fmaxf(e0, e1), fmaxf(e2, e3));
        if (em > m + THR) {                    // wave-uniform
            float sc = __expf(m - em);
            ssum *= sc;
#pragma unroll
            for (int j = 0; j < V; ++j) acc[j] *= sc;
            m = em;
        }
        float w0 = __expf(e0 - m), w1 = __expf(e1 - m);
        float w2 = __expf(e2 - m), w3 = __expf(e3 - m);
        ssum += (w0 + w1) + (w2 + w3);
#pragma unroll
        for (int j = 0; j < V; ++j)
            acc[j] += (w0 * row0[j] + w1 * row1[j]) + (w2 * row2[j] + w3 * row3[j]);
    }
    for (; k < s1; ++k) {
        int r0 = esrc[k];
        float row0[V];
        if (V == 4) {
            ushort4 v0 = *(const ushort4*)(H + (size_t)r0 * F + lane * 4);
            row0[0] = b2f(v0.x); row0[1] = b2f(v0.y); row0[2] = b2f(v0.z); row0[3] = b2f(v0.w);
        } else {
            ushort2 v0 = *(const ushort2*)(H + (size_t)r0 * F + lane * 2);
            row0[0] = b2f(v0.x); row0[1] = b2f(v0.y);
        }
        float e0 = as[r0] + adi; e0 = e0 > 0.f ? e0 : 0.2f * e0;
        if (e0 > m + THR) {
            float sc = __expf(m - e0);
            ssum *= sc;
#pragma unroll
            for (int j = 0; j < V; ++j) acc[j] *= sc;
            m = e0;
        }
        float w0 = __expf(e0 - m);
        ssum += w0;
#pragma unroll
        for (int j = 0; j < V; ++j) acc[j] += w0 * row0[j];
    }
    float inv = 1.f / ssum;
    float r[V];
#pragma unroll
    for (int j = 0; j < V; ++j) {
        r[j] = acc[j] * inv + bias[lane * V + j];
        if (RELU) r[j] = fmaxf(r[j], 0.f);
    }
    if (V == 4) *(float4*)(out + (size_t)gw * F + lane * 4) = make_float4(r[0], r[1], r[2], r[3]);
    else        *(float2*)(out + (size_t)gw * F + lane * 2) = make_float2(r[0], r[1]);
    if constexpr (WB && V == 4) {
        ushort4 h4;
        h4.x = f2bf(r[0]); h4.y = f2bf(r[1]); h4.z = f2bf(r[2]); h4.w = f2bf(r[3]);
        *(ushort4*)(hb + (size_t)gw * F + lane * 4) = h4;
    }
}

// ---------------- launch ----------------

static inline size_t al256(size_t x) { return (x + 255) & ~(size_t)255; }

extern "C" void kernel_launch(void* const* d_in, const int* in_sizes, int n_in,
                              void* d_out, int out_size, void* d_ws, size_t ws_size,
                              hipStream_t stream) {
    const float* x   = (const float*)d_in[0];
    const int*   ei  = (const int*)d_in[1];
    const float* W1  = (const float*)d_in[2];
    const float* as1 = (const float*)d_in[3];
    const float* ad1 = (const float*)d_in[4];
    const float* b1  = (const float*)d_in[5];
    const float* W2  = (const float*)d_in[6];
    const float* as2 = (const float*)d_in[7];
    const float* ad2 = (const float*)d_in[8];
    const float* b2  = (const float*)d_in[9];

    float* out_x2 = (float*)d_out;                          // [50000,128]
    float* out_h  = (float*)d_out + (size_t)N_NODES * 128;  // [50000,256] fp32

    const size_t NM256 = (size_t)N_NODES * 256 * 2;         // bf16 [50000][256]
    char* base = (char*)d_ws;
    size_t off = 0;
    auto take = [&](size_t bytes) { char* p = base + off; off = al256(off + bytes); return p; };

    ushort* h1b  = (ushort*)take(NM256);            // layer1 GEMM out (bf16); reused as layer2 gb
    ushort* xb   = (ushort*)take(NM256);            // RNE bf16 of x (layer1 GEMM A)
    ushort* hb   = (ushort*)take(NM256);            // RNE bf16 of relu(out_h) (layer2 GEMM A)
    ushort* w1th = (ushort*)take(256 * 256 * 2);
    ushort* w1tl = (ushort*)take(256 * 256 * 2);
    ushort* w2th = (ushort*)take(256 * 128 * 2);
    ushort* w2tl = (ushort*)take(256 * 128 * 2);
    float*  asb  = (float*)take(N_NODES * 4);
    float*  adb  = (float*)take(N_NODES * 4);
    int*    deg  = (int*)take(N_NODES * 4);
    int*    offs = (int*)take((N_NODES + 4) * 4);
    int*    curs = (int*)take((N_NODES + 4) * 4);
    int*    bsum = (int*)take(1024);
    int*    esrc = (int*)take((size_t)ETOT * 4);
    (void)ws_size;

    hipMemsetAsync(deg, 0, N_NODES * sizeof(int), stream);

    int nbE = (ETOT + 255) / 256;
    int nbN = (N_NODES + 255) / 256;
    int nbW = (N_NODES * 64 + 255) / 256;       // one wave per node

    // CSR by dst
    k_deg<<<nbE, 256, 0, stream>>>(ei, deg);
    k_scan1<<<nbN, 256, 0, stream>>>(deg, offs, bsum);
    k_scan2<<<1, 256, 0, stream>>>(bsum, nbN);
    k_scan3<<<nbN, 256, 0, stream>>>(offs, bsum, curs);
    k_scatter<<<nbE, 256, 0, stream>>>(ei, curs, esrc);

    // operand conversion (tiny + one full pass over x)
    k_splitT<<<(256 * 256 + 255) / 256, 256, 0, stream>>>(W1, w1th, w1tl, 256, 256);
    k_splitT<<<(256 * 128 + 255) / 256, 256, 0, stream>>>(W2, w2th, w2tl, 256, 128);
    k_split1<<<(N_NODES * 256 / 4 + 255) / 256, 256, 0, stream>>>(x, xb, N_NODES * 256 / 4);

    dim3 g1((N_NODES + 127) / 128, 4), g2((N_NODES + 127) / 128, 2);   // 64-wide col tiles

    // ---- layer 1
    k_gemm_mfma<<<g1, 256, 0, stream>>>(xb, w1th, w1tl, h1b, N_NODES, 256);
    k_alpha<256><<<nbW, 256, 0, stream>>>(h1b, as1, ad1, asb, adb);
    k_aggf<256, true, true><<<nbW, 256, 0, stream>>>(offs, esrc, asb, adb, h1b, b1, out_h, hb);

    // ---- layer 2 (A = hb bf16; gb reuses h1b)
    ushort* gb = h1b;
    k_gemm_mfma<<<g2, 256, 0, stream>>>(hb, w2th, w2tl, gb, N_NODES, 128);
    k_alpha<128><<<nbW, 256, 0, stream>>>(gb, as2, ad2, asb, adb);
    k_aggf<128, false, false><<<nbW, 256, 0, stream>>>(offs, esrc, asb, adb, gb, b2, out_x2, nullptr);
}

// Round 15
// 296.981 us; speedup vs baseline: 1.0740x; 1.0740x over previous
//
#include <hip/hip_runtime.h>
#include <hip/hip_bf16.h>

#define N_NODES 50000
#define E0      800000
#define ETOT    850000

typedef __bf16 bf16x8 __attribute__((ext_vector_type(8)));
typedef float  f32x4  __attribute__((ext_vector_type(4)));
typedef ushort u16x8  __attribute__((ext_vector_type(8)));
union B8 { u16x8 u; bf16x8 b; };

static __device__ __forceinline__ float b2f(ushort u) {
    union { uint u; float f; } x; x.u = ((uint)u) << 16; return x.f;
}
static __device__ __forceinline__ ushort f2bf(float f) {
    uint u = __builtin_bit_cast(uint, f);
    uint r = (u + 0x7FFFu + ((u >> 16) & 1u)) >> 16;   // RNE; inputs finite
    return (ushort)r;
}

// ---------------- CSR build ----------------

__global__ __launch_bounds__(256) void k_deg(const int* __restrict__ ei, int* __restrict__ deg) {
    int e = blockIdx.x * 256 + threadIdx.x;
    if (e >= ETOT) return;
    int dst = (e < E0) ? ei[E0 + e] : (e - E0);
    atomicAdd(&deg[dst], 1);
}

__global__ __launch_bounds__(256) void k_scan1(const int* __restrict__ deg, int* __restrict__ offs,
                                               int* __restrict__ bsum) {
    __shared__ int buf[256];
    int tid = threadIdx.x;
    int i = blockIdx.x * 256 + tid;
    int v = (i < N_NODES) ? deg[i] : 0;
    buf[tid] = v;
    __syncthreads();
    for (int off = 1; off < 256; off <<= 1) {
        int t = (tid >= off) ? buf[tid - off] : 0;
        __syncthreads();
        buf[tid] += t;
        __syncthreads();
    }
    if (i < N_NODES) offs[i + 1] = buf[tid];
    if (tid == 255) bsum[blockIdx.x] = buf[255];
}

__global__ __launch_bounds__(256) void k_scan2(int* __restrict__ bsum, int nb) {
    __shared__ int buf[256];
    int tid = threadIdx.x;
    int v = (tid < nb) ? bsum[tid] : 0;
    buf[tid] = v;
    __syncthreads();
    for (int off = 1; off < 256; off <<= 1) {
        int t = (tid >= off) ? buf[tid - off] : 0;
        __syncthreads();
        buf[tid] += t;
        __syncthreads();
    }
    if (tid < nb) bsum[tid] = buf[tid] - v;
}

// also fills cursor (saves a kernel)
__global__ __launch_bounds__(256) void k_scan3(int* __restrict__ offs, const int* __restrict__ bsum,
                                               int* __restrict__ cursor) {
    int tid = threadIdx.x;
    int i = blockIdx.x * 256 + tid;
    if (i < N_NODES) {
        int v = offs[i + 1] + bsum[blockIdx.x];
        offs[i + 1] = v;
        cursor[i + 1] = v;
    }
    if (i == 0) { offs[0] = 0; cursor[0] = 0; }
}

__global__ __launch_bounds__(256) void k_scatter(const int* __restrict__ ei, int* __restrict__ cursor,
                                                 int* __restrict__ esrc) {
    int e = blockIdx.x * 256 + threadIdx.x;
    if (e >= ETOT) return;
    int src, dst;
    if (e < E0) { src = ei[e]; dst = ei[E0 + e]; }
    else        { src = e - E0; dst = src; }
    int pos = atomicAdd(&cursor[dst], 1);
    esrc[pos] = src;
}

// W [K][N] fp32 -> Wt_hi/Wt_lo [N][K] bf16 (tiny)
__global__ __launch_bounds__(256) void k_splitT(const float* __restrict__ W, ushort* __restrict__ th,
                                                ushort* __restrict__ tl, int K, int N) {
    int i = blockIdx.x * 256 + threadIdx.x;
    if (i >= K * N) return;
    int n = i / K, k = i - n * K;
    float v = W[(size_t)k * N + n];
    ushort h = f2bf(v);
    th[(size_t)n * K + k] = h;
    tl[(size_t)n * K + k] = f2bf(v - b2f(h));
}

// fp32 -> single RNE bf16 (for GEMM A)
__global__ __launch_bounds__(256) void k_split1(const float* __restrict__ in, ushort* __restrict__ out, int n4) {
    int i = blockIdx.x * 256 + threadIdx.x;
    if (i >= n4) return;
    float4 v = *(const float4*)(in + (size_t)i * 4);
    ushort4 h;
    h.x = f2bf(v.x); h.y = f2bf(v.y); h.z = f2bf(v.z); h.w = f2bf(v.w);
    *(ushort4*)(out + (size_t)i * 4) = h;
}

// ---------------- MFMA GEMM: A bf16 (pre-rounded), B hi/lo LDS dbuf ----------------
// Cb[M][Nn](bf16) = Ab[M][K=256](bf16) @ (Bth+Btl)[Nn][K]^T
// 128x128 tile, 4 waves (2x2), 64x64/wave. BK=64 windows, LDS 64KB.
// 2 MFMA streams: A*Bh + A*Bl.  [R13 config — best measured; frozen]

__global__ __launch_bounds__(256, 2) void k_gemm_mfma(const ushort* __restrict__ Ab,
                                                      const ushort* __restrict__ Bth,
                                                      const ushort* __restrict__ Btl,
                                                      ushort* __restrict__ Cb, int M, int Nn) {
    constexpr int K = 256;
    __shared__ ushort lds[2][2][8][128][8];      // 64 KB
    int tid = threadIdx.x;
    int wid = tid >> 6, lane = tid & 63;
    int wr = wid >> 1, wc = wid & 1;
    int bm = blockIdx.x * 128, bn = blockIdx.y * 128;
    int lr = lane & 15, lg = lane >> 4;

    // staging role: thread t covers array sa (0=hi,1=lo), column scol
    int sa = tid >> 7, scol = tid & 127;
    const ushort* sb = (sa ? Btl : Bth) + (size_t)(bn + scol) * K;

    const ushort* Ap[4];
#pragma unroll
    for (int m = 0; m < 4; ++m) {
        int row = bm + wr * 64 + m * 16 + lr;
        if (row >= M) row = M - 1;
        Ap[m] = Ab + (size_t)row * K + lg * 8;
    }

    f32x4 acc[4][4] = {};
    u16x8 sv[8];
    bf16x8 aH[2][4];

    // prologue: stage window 0, prefetch A steps 0,1
#pragma unroll
    for (int c = 0; c < 8; ++c) sv[c] = *(const u16x8*)(sb + c * 8);
#pragma unroll
    for (int m = 0; m < 4; ++m) {
        aH[0][m] = *(const bf16x8*)(Ap[m]);
        aH[1][m] = *(const bf16x8*)(Ap[m] + 32);
    }
#pragma unroll
    for (int c = 0; c < 8; ++c) *(u16x8*)&lds[0][sa][c][scol][0] = sv[c];
    __syncthreads();

#pragma unroll
    for (int s = 0; s < 8; ++s) {               // K32 steps; window w = s/2
        const int w = s >> 1, buf = w & 1, kk = s & 1;
        if (kk == 0 && w < 3) {                 // issue next window's B loads
#pragma unroll
            for (int c = 0; c < 8; ++c) sv[c] = *(const u16x8*)(sb + (w + 1) * 64 + c * 8);
        }
        bf16x8 bh[4], bl[4];
#pragma unroll
        for (int n = 0; n < 4; ++n) {
            int col = wc * 64 + n * 16 + lr;
            B8 th, tl2;
            th.u = *(const u16x8*)&lds[buf][0][kk * 4 + lg][col][0];
            tl2.u = *(const u16x8*)&lds[buf][1][kk * 4 + lg][col][0];
            bh[n] = th.b; bl[n] = tl2.b;
        }
        bf16x8 ah[4];
#pragma unroll
        for (int m = 0; m < 4; ++m) ah[m] = aH[s & 1][m];
        if (s < 6) {                            // refill this slot for step s+2
#pragma unroll
            for (int m = 0; m < 4; ++m) aH[s & 1][m] = *(const bf16x8*)(Ap[m] + (s + 2) * 32);
        }
#pragma unroll
        for (int m = 0; m < 4; ++m)
#pragma unroll
            for (int n = 0; n < 4; ++n) {
                acc[m][n] = __builtin_amdgcn_mfma_f32_16x16x32_bf16(ah[m], bh[n], acc[m][n], 0, 0, 0);
                acc[m][n] = __builtin_amdgcn_mfma_f32_16x16x32_bf16(ah[m], bl[n], acc[m][n], 0, 0, 0);
            }
        if (kk == 1 && w < 3) {                 // commit next window into other buffer
#pragma unroll
            for (int c = 0; c < 8; ++c) *(u16x8*)&lds[buf ^ 1][sa][c][scol][0] = sv[c];
            __syncthreads();
        }
    }
    // C/D layout: col = lane&15, row = (lane>>4)*4 + reg   [m89-verified]
#pragma unroll
    for (int m = 0; m < 4; ++m)
#pragma unroll
        for (int r = 0; r < 4; ++r) {
            int row = bm + wr * 64 + m * 16 + lg * 4 + r;
            if (row < M) {
#pragma unroll
                for (int n = 0; n < 4; ++n) {
                    int col = bn + wc * 64 + n * 16 + lr;
                    Cb[(size_t)row * Nn + col] = f2bf(acc[m][n][r]);
                }
            }
        }
}

// ---------------- per-node kernels (one wave / node), bf16 h rows ----------------

template <int F>
__global__ __launch_bounds__(256) void k_alpha(const ushort* __restrict__ H, const float* __restrict__ a_src,
                                               const float* __restrict__ a_dst, float* __restrict__ as,
                                               float* __restrict__ ad) {
    int gw = (blockIdx.x * 256 + threadIdx.x) >> 6;
    int lane = threadIdx.x & 63;
    if (gw >= N_NODES) return;
    float s = 0.f, d = 0.f;
    if (F == 256) {
        ushort4 v = *(const ushort4*)(H + (size_t)gw * 256 + lane * 4);
        float4 cs = *(const float4*)(a_src + lane * 4);
        float4 cd = *(const float4*)(a_dst + lane * 4);
        float f0 = b2f(v.x), f1 = b2f(v.y), f2 = b2f(v.z), f3 = b2f(v.w);
        s = f0 * cs.x + f1 * cs.y + f2 * cs.z + f3 * cs.w;
        d = f0 * cd.x + f1 * cd.y + f2 * cd.z + f3 * cd.w;
    } else {
        ushort2 v = *(const ushort2*)(H + (size_t)gw * 128 + lane * 2);
        float2 cs = *(const float2*)(a_src + lane * 2);
        float2 cd = *(const float2*)(a_dst + lane * 2);
        float f0 = b2f(v.x), f1 = b2f(v.y);
        s = f0 * cs.x + f1 * cs.y;
        d = f0 * cd.x + f1 * cd.y;
    }
    for (int o = 32; o; o >>= 1) { s += __shfl_down(s, o); d += __shfl_down(d, o); }
    if (lane == 0) { as[gw] = s; ad[gw] = d; }
}

// ---- fused online-softmax aggregation, 8-edge deep unroll + deferred rescale ----
// All 8 gathers issued before compute -> 8 rows in flight per wave (MLP).
// WB: also write RNE-bf16 copy of the (relu'd) result for next layer's GEMM A.
template <int F, bool RELU, bool WB>
__global__ __launch_bounds__(256) void k_aggf(const int* __restrict__ offs, const int* __restrict__ esrc,
                                              const float* __restrict__ as, const float* __restrict__ ad,
                                              const ushort* __restrict__ H, const float* __restrict__ bias,
                                              float* __restrict__ out, ushort* __restrict__ hb) {
    constexpr int V = F / 64;
    constexpr float THR = 8.f;
    int gw = (blockIdx.x * 256 + threadIdx.x) >> 6;
    int lane = threadIdx.x & 63;
    if (gw >= N_NODES) return;
    int s0 = offs[gw], s1 = offs[gw + 1];
    float adi = ad[gw];
    float m = -1e30f, ssum = 0.f;
    float acc[V] = {};
    int k = s0;
    for (; k + 7 < s1; k += 8) {
        int rr[8];
#pragma unroll
        for (int q = 0; q < 8; ++q) rr[q] = esrc[k + q];
        float ev[8];
#pragma unroll
        for (int q = 0; q < 8; ++q) ev[q] = as[rr[q]];
        float rows[8][V];
#pragma unroll
        for (int q = 0; q < 8; ++q) {
            if (V == 4) {
                ushort4 v = *(const ushort4*)(H + (size_t)rr[q] * F + lane * 4);
                rows[q][0] = b2f(v.x); rows[q][1] = b2f(v.y); rows[q][2] = b2f(v.z); rows[q][3] = b2f(v.w);
            } else {
                ushort2 v = *(const ushort2*)(H + (size_t)rr[q] * F + lane * 2);
                rows[q][0] = b2f(v.x); rows[q][1] = b2f(v.y);
            }
        }
        float em = -1e30f;
#pragma unroll
        for (int q = 0; q < 8; ++q) {
            float e = ev[q] + adi;
            e = e > 0.f ? e : 0.2f * e;
            ev[q] = e;
            em = fmaxf(em, e);
        }
        if (em > m + THR) {                    // wave-uniform
            float sc = __expf(m - em);
            ssum *= sc;
#pragma unroll
            for (int j = 0; j < V; ++j) acc[j] *= sc;
            m = em;
        }
        float w[8];
#pragma unroll
        for (int q = 0; q < 8; ++q) w[q] = __expf(ev[q] - m);
#pragma unroll
        for (int q = 0; q < 8; ++q) ssum += w[q];
#pragma unroll
        for (int j = 0; j < V; ++j) {
            float a = acc[j];
#pragma unroll
            for (int q = 0; q < 8; ++q) a += w[q] * rows[q][j];
            acc[j] = a;
        }
    }
    for (; k + 3 < s1; k += 4) {
        int rr[4];
#pragma unroll
        for (int q = 0; q < 4; ++q) rr[q] = esrc[k + q];
        float ev[4];
#pragma unroll
        for (int q = 0; q < 4; ++q) ev[q] = as[rr[q]];
        float rows[4][V];
#pragma unroll
        for (int q = 0; q < 4; ++q) {
            if (V == 4) {
                ushort4 v = *(const ushort4*)(H + (size_t)rr[q] * F + lane * 4);
                rows[q][0] = b2f(v.x); rows[q][1] = b2f(v.y); rows[q][2] = b2f(v.z); rows[q][3] = b2f(v.w);
            } else {
                ushort2 v = *(const ushort2*)(H + (size_t)rr[q] * F + lane * 2);
                rows[q][0] = b2f(v.x); rows[q][1] = b2f(v.y);
            }
        }
        float em = -1e30f;
#pragma unroll
        for (int q = 0; q < 4; ++q) {
            float e = ev[q] + adi;
            e = e > 0.f ? e : 0.2f * e;
            ev[q] = e;
            em = fmaxf(em, e);
        }
        if (em > m + THR) {
            float sc = __expf(m - em);
            ssum *= sc;
#pragma unroll
            for (int j = 0; j < V; ++j) acc[j] *= sc;
            m = em;
        }
        float w[4];
#pragma unroll
        for (int q = 0; q < 4; ++q) w[q] = __expf(ev[q] - m);
#pragma unroll
        for (int q = 0; q < 4; ++q) ssum += w[q];
#pragma unroll
        for (int j = 0; j < V; ++j) {
            float a = acc[j];
#pragma unroll
            for (int q = 0; q < 4; ++q) a += w[q] * rows[q][j];
            acc[j] = a;
        }
    }
    for (; k < s1; ++k) {
        int r0 = esrc[k];
        float row0[V];
        if (V == 4) {
            ushort4 v0 = *(const ushort4*)(H + (size_t)r0 * F + lane * 4);
            row0[0] = b2f(v0.x); row0[1] = b2f(v0.y); row0[2] = b2f(v0.z); row0[3] = b2f(v0.w);
        } else {
            ushort2 v0 = *(const ushort2*)(H + (size_t)r0 * F + lane * 2);
            row0[0] = b2f(v0.x); row0[1] = b2f(v0.y);
        }
        float e0 = as[r0] + adi; e0 = e0 > 0.f ? e0 : 0.2f * e0;
        if (e0 > m + THR) {
            float sc = __expf(m - e0);
            ssum *= sc;
#pragma unroll
            for (int j = 0; j < V; ++j) acc[j] *= sc;
            m = e0;
        }
        float w0 = __expf(e0 - m);
        ssum += w0;
#pragma unroll
        for (int j = 0; j < V; ++j) acc[j] += w0 * row0[j];
    }
    float inv = 1.f / ssum;
    float r[V];
#pragma unroll
    for (int j = 0; j < V; ++j) {
        r[j] = acc[j] * inv + bias[lane * V + j];
        if (RELU) r[j] = fmaxf(r[j], 0.f);
    }
    if (V == 4) *(float4*)(out + (size_t)gw * F + lane * 4) = make_float4(r[0], r[1], r[2], r[3]);
    else        *(float2*)(out + (size_t)gw * F + lane * 2) = make_float2(r[0], r[1]);
    if constexpr (WB && V == 4) {
        ushort4 h4;
        h4.x = f2bf(r[0]); h4.y = f2bf(r[1]); h4.z = f2bf(r[2]); h4.w = f2bf(r[3]);
        *(ushort4*)(hb + (size_t)gw * F + lane * 4) = h4;
    }
}

// ---------------- launch ----------------

static inline size_t al256(size_t x) { return (x + 255) & ~(size_t)255; }

extern "C" void kernel_launch(void* const* d_in, const int* in_sizes, int n_in,
                              void* d_out, int out_size, void* d_ws, size_t ws_size,
                              hipStream_t stream) {
    const float* x   = (const float*)d_in[0];
    const int*   ei  = (const int*)d_in[1];
    const float* W1  = (const float*)d_in[2];
    const float* as1 = (const float*)d_in[3];
    const float* ad1 = (const float*)d_in[4];
    const float* b1  = (const float*)d_in[5];
    const float* W2  = (const float*)d_in[6];
    const float* as2 = (const float*)d_in[7];
    const float* ad2 = (const float*)d_in[8];
    const float* b2  = (const float*)d_in[9];

    float* out_x2 = (float*)d_out;                          // [50000,128]
    float* out_h  = (float*)d_out + (size_t)N_NODES * 128;  // [50000,256] fp32

    const size_t NM256 = (size_t)N_NODES * 256 * 2;         // bf16 [50000][256]
    char* base = (char*)d_ws;
    size_t off = 0;
    auto take = [&](size_t bytes) { char* p = base + off; off = al256(off + bytes); return p; };

    ushort* h1b  = (ushort*)take(NM256);            // layer1 GEMM out (bf16); reused as layer2 gb
    ushort* xb   = (ushort*)take(NM256);            // RNE bf16 of x (layer1 GEMM A)
    ushort* hb   = (ushort*)take(NM256);            // RNE bf16 of relu(out_h) (layer2 GEMM A)
    ushort* w1th = (ushort*)take(256 * 256 * 2);
    ushort* w1tl = (ushort*)take(256 * 256 * 2);
    ushort* w2th = (ushort*)take(256 * 128 * 2);
    ushort* w2tl = (ushort*)take(256 * 128 * 2);
    float*  asb  = (float*)take(N_NODES * 4);
    float*  adb  = (float*)take(N_NODES * 4);
    int*    deg  = (int*)take(N_NODES * 4);
    int*    offs = (int*)take((N_NODES + 4) * 4);
    int*    curs = (int*)take((N_NODES + 4) * 4);
    int*    bsum = (int*)take(1024);
    int*    esrc = (int*)take((size_t)ETOT * 4);
    (void)ws_size;

    hipMemsetAsync(deg, 0, N_NODES * sizeof(int), stream);

    int nbE = (ETOT + 255) / 256;
    int nbN = (N_NODES + 255) / 256;
    int nbW = (N_NODES * 64 + 255) / 256;       // one wave per node

    // CSR by dst
    k_deg<<<nbE, 256, 0, stream>>>(ei, deg);
    k_scan1<<<nbN, 256, 0, stream>>>(deg, offs, bsum);
    k_scan2<<<1, 256, 0, stream>>>(bsum, nbN);
    k_scan3<<<nbN, 256, 0, stream>>>(offs, bsum, curs);
    k_scatter<<<nbE, 256, 0, stream>>>(ei, curs, esrc);

    // operand conversion (tiny + one full pass over x)
    k_splitT<<<(256 * 256 + 255) / 256, 256, 0, stream>>>(W1, w1th, w1tl, 256, 256);
    k_splitT<<<(256 * 128 + 255) / 256, 256, 0, stream>>>(W2, w2th, w2tl, 256, 128);
    k_split1<<<(N_NODES * 256 / 4 + 255) / 256, 256, 0, stream>>>(x, xb, N_NODES * 256 / 4);

    dim3 g1((N_NODES + 127) / 128, 2), g2((N_NODES + 127) / 128, 1);

    // ---- layer 1
    k_gemm_mfma<<<g1, 256, 0, stream>>>(xb, w1th, w1tl, h1b, N_NODES, 256);
    k_alpha<256><<<nbW, 256, 0, stream>>>(h1b, as1, ad1, asb, adb);
    k_aggf<256, true, true><<<nbW, 256, 0, stream>>>(offs, esrc, asb, adb, h1b, b1, out_h, hb);

    // ---- layer 2 (A = hb bf16; gb reuses h1b)
    ushort* gb = h1b;
    k_gemm_mfma<<<g2, 256, 0, stream>>>(hb, w2th, w2tl, gb, N_NODES, 128);
    k_alpha<128><<<nbW, 256, 0, stream>>>(gb, as2, ad2, asb, adb);
    k_aggf<128, false, false><<<nbW, 256, 0, stream>>>(offs, esrc, asb, adb, gb, b2, out_x2, nullptr);
}